// Round 1
// baseline (719.662 us; speedup 1.0000x reference)
//
#include <hip/hip_runtime.h>
#include <hip/hip_bf16.h>
#include <cstdint>
#include <cstddef>

// ---------------------------------------------------------------------------
// Problem constants
//   x:    [B=128, T=256, D=1024] fp32
//   Wk:   [1024, 512]  (per dir)   Wr: [128, 512]   bias: [512]
//   xp[dir][b*256+t][512] = x[b,t,:] @ Wk        (bias added in recurrence)
//   LSTM per (dir,b) sequence; gates order i,f,g,o in 128-chunks.
//   head: relu(hcat @ W1 + b1) @ W2 + b2 -> sigmoid -> out [128,2]
// ---------------------------------------------------------------------------

typedef __attribute__((ext_vector_type(8))) short short8;
typedef __attribute__((ext_vector_type(4))) float f32x4;

__device__ __forceinline__ unsigned short f2b(float f) {
    unsigned int u = __float_as_uint(f);
    u += 0x7FFFu + ((u >> 16) & 1u);          // round-to-nearest-even
    return (unsigned short)(u >> 16);
}
__device__ __forceinline__ float b2f(unsigned short u) {
    return __uint_as_float(((unsigned int)u) << 16);
}
__device__ __forceinline__ float sigmoidf_(float z) { return 1.0f / (1.0f + __expf(-z)); }
__device__ __forceinline__ float tanhf_(float z) {
    float e = __expf(2.0f * z);
    return 1.0f - 2.0f / (e + 1.0f);
}

// ---------------------------------------------------------------------------
// Kernel 1: convert x fp32 -> bf16 (same layout), 8 elems/thread/iter
// ---------------------------------------------------------------------------
__global__ void conv_x(const float* __restrict__ x, unsigned short* __restrict__ xb, int n8) {
    int idx = blockIdx.x * blockDim.x + threadIdx.x;
    int stride = gridDim.x * blockDim.x;
    for (int i = idx; i < n8; i += stride) {
        const float4* p = ((const float4*)x) + (size_t)i * 2;
        float4 a = p[0], b = p[1];
        short8 r;
        r[0] = (short)f2b(a.x); r[1] = (short)f2b(a.y);
        r[2] = (short)f2b(a.z); r[3] = (short)f2b(a.w);
        r[4] = (short)f2b(b.x); r[5] = (short)f2b(b.y);
        r[6] = (short)f2b(b.z); r[7] = (short)f2b(b.w);
        *(((short8*)xb) + i) = r;
    }
}

// ---------------------------------------------------------------------------
// Kernel 2: transpose + convert Wk [1024][512] fp32 -> Wk_t [512][1024] bf16
// grid (2048, 2) x 256
// ---------------------------------------------------------------------------
__global__ void conv_wk(const float* __restrict__ wf, const float* __restrict__ wb,
                        unsigned short* __restrict__ wt) {
    int dir = blockIdx.y;
    const float* w = dir ? wb : wf;
    int id = blockIdx.x * blockDim.x + threadIdx.x;   // 0 .. 524287
    int g = id >> 10, d = id & 1023;
    wt[(size_t)dir * 524288 + id] = f2b(w[d * 512 + g]);
}

// ---------------------------------------------------------------------------
// Kernel 3: GEMM  xp[dir] = A(bf16)[32768,1024] @ Wk_t[dir]^T  -> [32768,512]
// 128x128 tile, BK=64, 4 waves (2x2 of 64x64), mfma_f32_16x16x32_bf16.
// LDS rows padded to 72 elems (144 B, 16B-aligned) to keep ds_read_b128 at
// <=2-way bank aliasing (free per m136).
// ---------------------------------------------------------------------------
#define LDK 72

template <typename XT>
__device__ __forceinline__ void store_xp(XT* p, float v);
template <>
__device__ __forceinline__ void store_xp<float>(float* p, float v) { *p = v; }
template <>
__device__ __forceinline__ void store_xp<unsigned short>(unsigned short* p, float v) { *p = f2b(v); }

template <typename XT>
__global__ __launch_bounds__(256, 2) void gemm_xp(
    const unsigned short* __restrict__ A,    // [32768][1024] bf16
    const unsigned short* __restrict__ Wt,   // [2][512][1024] bf16
    XT* __restrict__ XP)                     // [2][32768][512]
{
    __shared__ unsigned short As[128 * LDK];
    __shared__ unsigned short Bs[128 * LDK];

    const int tid  = threadIdx.x;
    const int dir  = blockIdx.z;
    const int tm   = blockIdx.x;             // 0..255
    const int tn   = blockIdx.y;             // 0..3
    const int w    = tid >> 6;
    const int lane = tid & 63;
    const int lanelo = lane & 15;
    const int quad = lane >> 4;
    const int wm = w & 1, wn = w >> 1;

    const unsigned short* Bmat = Wt + (size_t)dir * 524288;
    XT* out = XP + (size_t)dir * 16777216;

    const int sr = tid >> 3;                 // 0..31 staging row
    const int sc = (tid & 7) * 8;            // elem col within BK

    f32x4 acc[4][4];
#pragma unroll
    for (int i = 0; i < 4; i++)
#pragma unroll
        for (int j = 0; j < 4; j++) acc[i][j] = (f32x4){0.f, 0.f, 0.f, 0.f};

    const unsigned short* Ag = A + (size_t)(tm * 128 + sr) * 1024 + sc;
    const unsigned short* Bg = Bmat + (size_t)(tn * 128 + sr) * 1024 + sc;

    for (int kt = 0; kt < 16; ++kt) {
        uint4 a0 = *(const uint4*)(Ag + kt * 64);
        uint4 a1 = *(const uint4*)(Ag + 32 * 1024 + kt * 64);
        uint4 a2 = *(const uint4*)(Ag + 64 * 1024 + kt * 64);
        uint4 a3 = *(const uint4*)(Ag + 96 * 1024 + kt * 64);
        uint4 b0 = *(const uint4*)(Bg + kt * 64);
        uint4 b1 = *(const uint4*)(Bg + 32 * 1024 + kt * 64);
        uint4 b2 = *(const uint4*)(Bg + 64 * 1024 + kt * 64);
        uint4 b3 = *(const uint4*)(Bg + 96 * 1024 + kt * 64);
        __syncthreads();
        *(uint4*)(As + (sr +  0) * LDK + sc) = a0;
        *(uint4*)(As + (sr + 32) * LDK + sc) = a1;
        *(uint4*)(As + (sr + 64) * LDK + sc) = a2;
        *(uint4*)(As + (sr + 96) * LDK + sc) = a3;
        *(uint4*)(Bs + (sr +  0) * LDK + sc) = b0;
        *(uint4*)(Bs + (sr + 32) * LDK + sc) = b1;
        *(uint4*)(Bs + (sr + 64) * LDK + sc) = b2;
        *(uint4*)(Bs + (sr + 96) * LDK + sc) = b3;
        __syncthreads();
#pragma unroll
        for (int ks = 0; ks < 2; ++ks) {
            short8 af[4], bf[4];
#pragma unroll
            for (int i = 0; i < 4; i++)
                af[i] = *(const short8*)(As + (wm * 64 + i * 16 + lanelo) * LDK + ks * 32 + quad * 8);
#pragma unroll
            for (int j = 0; j < 4; j++)
                bf[j] = *(const short8*)(Bs + (wn * 64 + j * 16 + lanelo) * LDK + ks * 32 + quad * 8);
#pragma unroll
            for (int i = 0; i < 4; i++)
#pragma unroll
                for (int j = 0; j < 4; j++)
                    acc[i][j] = __builtin_amdgcn_mfma_f32_16x16x32_bf16(af[i], bf[j], acc[i][j], 0, 0, 0);
        }
    }

    // epilogue: C/D layout col=lane&15, row=quad*4+reg
#pragma unroll
    for (int i = 0; i < 4; i++) {
        int row0 = tm * 128 + wm * 64 + i * 16 + quad * 4;
#pragma unroll
        for (int j = 0; j < 4; j++) {
            int col = tn * 128 + wn * 64 + j * 16 + lanelo;
#pragma unroll
            for (int r = 0; r < 4; r++)
                store_xp<XT>(out + (size_t)(row0 + r) * 512 + col, acc[i][j][r]);
        }
    }
}

// ---------------------------------------------------------------------------
// Kernel 4: LSTM recurrence. One block (256 thr, 4 waves) per (dir, b) pair.
// Wr lives in registers as MFMA B-frags (wave w owns gates [128w, 128w+128)
// == exactly one gate type). h broadcast each step via LDS tile in A-layout.
// ---------------------------------------------------------------------------
template <typename XT>
__device__ __forceinline__ float2 load_x2(const XT* p);
template <>
__device__ __forceinline__ float2 load_x2<float>(const float* p) { return *(const float2*)p; }
template <>
__device__ __forceinline__ float2 load_x2<unsigned short>(const unsigned short* p) {
    unsigned int u = *(const unsigned int*)p;
    float2 r;
    r.x = b2f((unsigned short)(u & 0xFFFFu));
    r.y = b2f((unsigned short)(u >> 16));
    return r;
}

template <typename XT>
__global__ __launch_bounds__(256, 1) void lstm_rec(
    const XT* __restrict__ XP,               // [2][32768][512]
    const float* __restrict__ Wfr, const float* __restrict__ Wbr,
    const float* __restrict__ bfv, const float* __restrict__ bbv,
    float* __restrict__ Hout)                // [2][128][128]
{
    __shared__ unsigned short h_lds[16 * 136]; // A-layout tile, rows 1..15 stay 0
    __shared__ float xbuf[2][512];
    __shared__ float zact[512];

    const int tid  = threadIdx.x;
    const int seq  = blockIdx.x;             // 0..255
    const int dir  = seq >> 7;
    const int b    = seq & 127;
    const int w    = tid >> 6;
    const int lane = tid & 63;
    const int lanelo = lane & 15;
    const int quad = lane >> 4;

    const float* Wr   = dir ? Wbr : Wfr;
    const float* bias = dir ? bbv : bfv;
    const XT* xp = XP + (size_t)dir * 16777216 + (size_t)b * 256 * 512;

    // --- one-time: load Wr into B-fragments (bf16) + bias ---
    short8 wrf[8][4];
    float biasv[8];
#pragma unroll
    for (int nt = 0; nt < 8; ++nt) {
        int g = w * 128 + nt * 16 + lanelo;
        biasv[nt] = bias[g];
#pragma unroll
        for (int ks = 0; ks < 4; ++ks) {
            short8 f;
#pragma unroll
            for (int j = 0; j < 8; ++j) {
                int k = ks * 32 + quad * 8 + j;
                f[j] = (short)f2b(Wr[k * 512 + g]);
            }
            wrf[nt][ks] = f;
        }
    }

    for (int i = tid; i < 16 * 136; i += 256) h_lds[i] = 0;

    float c_reg = 0.0f;
    float h_final = 0.0f;

    // depth-2 prefetch of xp rows
    float2 xA = load_x2<XT>(xp + (size_t)(dir ? 255 : 0) * 512 + 2 * tid);
    float2 xB = load_x2<XT>(xp + (size_t)(dir ? 254 : 1) * 512 + 2 * tid);

    for (int t = 0; t < 256; ++t) {
        *(float2*)(&xbuf[t & 1][tid * 2]) = xA;
        __syncthreads();   // (1) xbuf + prev h_lds visible
        xA = xB;
        if (t + 2 < 256) {
            int te = dir ? (253 - t) : (t + 2);
            xB = load_x2<XT>(xp + (size_t)te * 512 + 2 * tid);
        }

        // h A-frags
        short8 af[4];
#pragma unroll
        for (int ks = 0; ks < 4; ++ks)
            af[ks] = *(const short8*)(h_lds + lanelo * 136 + ks * 32 + quad * 8);

#pragma unroll
        for (int nt = 0; nt < 8; ++nt) {
            float c0 = xbuf[t & 1][w * 128 + nt * 16 + lanelo] + biasv[nt];
            f32x4 acc = (f32x4){c0, c0, c0, c0};
#pragma unroll
            for (int ks = 0; ks < 4; ++ks)
                acc = __builtin_amdgcn_mfma_f32_16x16x32_bf16(af[ks], wrf[nt][ks], acc, 0, 0, 0);
            float z = acc[0];                // valid on quad==0 lanes (row 0)
            float a = (w == 2) ? tanhf_(z) : sigmoidf_(z);
            if (lane < 16) zact[w * 128 + nt * 16 + lane] = a;
        }
        __syncthreads();   // (2) zact complete

        if (tid < 128) {
            float iv = zact[tid];
            float fv = zact[128 + tid];
            float gv = zact[256 + tid];
            float ov = zact[384 + tid];
            c_reg = fv * c_reg + iv * gv;
            float h = ov * tanhf_(c_reg);
            h_lds[tid] = f2b(h);             // row 0 of A-tile
            if (t == 255) h_final = h;
        }
    }

    if (tid < 128) Hout[(size_t)seq * 128 + tid] = h_final;
}

// ---------------------------------------------------------------------------
// Kernel 5: MLP head. One block (64 thr) per batch row.
// ---------------------------------------------------------------------------
__global__ void mlp_head(const float* __restrict__ Hout,
                         const float* __restrict__ W1, const float* __restrict__ b1,
                         const float* __restrict__ W2, const float* __restrict__ b2,
                         float* __restrict__ out)
{
    __shared__ float y1[32];
    int b = blockIdx.x;
    int j = threadIdx.x;
    const float* hf = Hout + (size_t)b * 128;
    const float* hb = Hout + (size_t)(128 + b) * 128;
    if (j < 32) {
        float acc = b1[j];
        for (int k = 0; k < 128; ++k) acc += hf[k] * W1[k * 32 + j];
        for (int k = 0; k < 128; ++k) acc += hb[k] * W1[(128 + k) * 32 + j];
        y1[j] = fmaxf(acc, 0.0f);
    }
    __syncthreads();
    if (j < 2) {
        float z = b2[j];
        for (int k = 0; k < 32; ++k) z += y1[k] * W2[k * 2 + j];
        out[b * 2 + j] = 1.0f / (1.0f + __expf(-z));
    }
}

// ---------------------------------------------------------------------------
extern "C" void kernel_launch(void* const* d_in, const int* in_sizes, int n_in,
                              void* d_out, int out_size, void* d_ws, size_t ws_size,
                              hipStream_t stream) {
    const float* x    = (const float*)d_in[0];
    const float* Wf_k = (const float*)d_in[1];
    const float* Wf_r = (const float*)d_in[2];
    const float* bf   = (const float*)d_in[3];
    const float* Wb_k = (const float*)d_in[4];
    const float* Wb_r = (const float*)d_in[5];
    const float* bb   = (const float*)d_in[6];
    const float* W1   = (const float*)d_in[7];
    const float* b1   = (const float*)d_in[8];
    const float* W2   = (const float*)d_in[9];
    const float* b2   = (const float*)d_in[10];
    float* out = (float*)d_out;

    char* ws = (char*)d_ws;
    const size_t OFF_XB   = 0;                       // 67,108,864 B  (x bf16)
    const size_t OFF_WT   = 67108864;                //  2,097,152 B  (Wk_t bf16 x2)
    const size_t OFF_HOUT = OFF_WT + 2097152;        //    131,072 B
    const size_t OFF_XP   = OFF_HOUT + 131072;       // xp: fp32 134,217,728 or bf16 67,108,864

    unsigned short* xb = (unsigned short*)(ws + OFF_XB);
    unsigned short* wt = (unsigned short*)(ws + OFF_WT);
    float*          ho = (float*)(ws + OFF_HOUT);
    void*           xp = (void*)(ws + OFF_XP);

    const bool xp_f32 = (ws_size >= OFF_XP + (size_t)134217728);

    conv_x<<<dim3(2048), dim3(256), 0, stream>>>(x, xb, 33554432 / 8);
    conv_wk<<<dim3(2048, 2), dim3(256), 0, stream>>>(Wf_k, Wb_k, wt);

    if (xp_f32) {
        gemm_xp<float><<<dim3(256, 4, 2), dim3(256), 0, stream>>>(xb, wt, (float*)xp);
        lstm_rec<float><<<dim3(256), dim3(256), 0, stream>>>((const float*)xp, Wf_r, Wb_r, bf, bb, ho);
    } else {
        gemm_xp<unsigned short><<<dim3(256, 4, 2), dim3(256), 0, stream>>>(xb, wt, (unsigned short*)xp);
        lstm_rec<unsigned short><<<dim3(256), dim3(256), 0, stream>>>((const unsigned short*)xp, Wf_r, Wb_r, bf, bb, ho);
    }

    mlp_head<<<dim3(128), dim3(64), 0, stream>>>(ho, W1, b1, W2, b2, out);
}